// Round 4
// baseline (6978.283 us; speedup 1.0000x reference)
//
#include <hip/hip_runtime.h>

#define N_CLOUDS 16
#define PTS      16384
#define M        4096
#define THREADS  1024
#define NWAVES   (THREADS / 64)    // 16 waves
#define NGROUPS  8                 // v2f groups/thread: 8*2 = 16 pts/thread

typedef float v2f __attribute__((ext_vector_type(2)));
typedef unsigned long long u64;
typedef unsigned int u32;

// One block per cloud; serial FPS, latency-optimized.
// Round-4 changes vs round 3:
//  - 1024 thr x 16 pts/thread: per-thread state = 64 floats + overhead < 128
//    VGPRs => no AGPR/scratch round-trip (round 3: 32 pts/thr needed ~160,
//    VGPR_Count=96 => ~640 cyc/iter of register-shuffle traffic).
//  - DPP wave reduce (row_shr 1/2/4/8 + row_bcast 15/31, result in lane 63)
//    at VALU latency instead of 6 dependent __shfl_down LDS-pipe hops.
// Kept: u64 key = (dist bits << 32) | ~li (first-occurrence argmax), one
// barrier/iter with parity-buffered skey, contract-off math (absmax=0).

#define GROUPS_X(X) X(0) X(1) X(2) X(3) X(4) X(5) X(6) X(7)

// u64 max with shifted copy from DPP (old=0 is identity for max: keys >= 0)
#define DPP_MAX_STEP(CTRL) { \
        const u32 lo  = (u32)key; \
        const u32 hi  = (u32)(key >> 32); \
        const u32 lo2 = (u32)__builtin_amdgcn_update_dpp(0, (int)lo, (CTRL), 0xf, 0xf, false); \
        const u32 hi2 = (u32)__builtin_amdgcn_update_dpp(0, (int)hi, (CTRL), 0xf, 0xf, false); \
        const u64 ok  = ((u64)hi2 << 32) | lo2; \
        key = (ok > key) ? ok : key; \
    }

__global__ __launch_bounds__(THREADS, 4) void fps_kernel(
    const float* __restrict__ pos, int* __restrict__ out)
{
#pragma clang fp contract(off)
    const int cloud = blockIdx.x;
    const int tid   = threadIdx.x;
    const int base  = cloud * PTS;

    __shared__ u64 skey[2][NWAVES];

    // ---- query = point 0 of cloud ----
    const float q0x = pos[(size_t)base * 3 + 0];
    const float q0y = pos[(size_t)base * 3 + 1];
    const float q0z = pos[(size_t)base * 3 + 2];
    v2f qx2 = {q0x, q0x}, qy2 = {q0y, q0y}, qz2 = {q0z, q0z};

    // ---- explicit register storage: 8 v2f per coord (slots 2j, 2j+1) ----
#define DECL(j) v2f px##j, py##j, pz##j, d##j;
    GROUPS_X(DECL)
#undef DECL

    float bd = -1.0f;   // lane-local running max of min-dists
    int   bk = 0;       // slot 0..15; li = tid + bk*THREADS

#define INIT(j) { \
        const int li0 = tid + (2*(j)) * THREADS; \
        const size_t o0 = (size_t)(base + li0) * 3; \
        const size_t o1 = o0 + (size_t)THREADS * 3; \
        px##j = (v2f){pos[o0 + 0], pos[o1 + 0]}; \
        py##j = (v2f){pos[o0 + 1], pos[o1 + 1]}; \
        pz##j = (v2f){pos[o0 + 2], pos[o1 + 2]}; \
        v2f dx = px##j - qx2; \
        v2f dy = py##j - qy2; \
        v2f dz = pz##j - qz2; \
        v2f nd = dx * dx + dy * dy + dz * dz; \
        d##j = nd; \
        if (nd.x > bd) { bd = nd.x; bk = 2*(j); } \
        if (nd.y > bd) { bd = nd.y; bk = 2*(j) + 1; } \
    }
    GROUPS_X(INIT)
#undef INIT

    if (tid == 0) out[cloud * M] = base;   // first sample = point 0

    const int wave = tid >> 6;
    const int lane = tid & 63;

    for (int i = 1; i < M; ++i) {
        // ---- u64 key: high = dist bits (>=0 so uint-monotone), low = ~li ----
        const int bi = tid + bk * THREADS;
        u64 key = ((u64)__float_as_uint(bd) << 32) | (u32)(~bi);

        // ---- wave max-reduce via DPP; full-wave max lands in lane 63 ----
        DPP_MAX_STEP(0x111)   // row_shr:1
        DPP_MAX_STEP(0x112)   // row_shr:2
        DPP_MAX_STEP(0x114)   // row_shr:4
        DPP_MAX_STEP(0x118)   // row_shr:8  -> lane 15 of each row = row max
        DPP_MAX_STEP(0x142)   // row_bcast:15 -> lane31=max(r0,r1), lane63=max(r2,r3)
        DPP_MAX_STEP(0x143)   // row_bcast:31 -> lane63 = full wave max

        if (lane == 63) skey[i & 1][wave] = key;
        __syncthreads();

        // ---- every thread reduces the 16 wave winners (deterministic) ----
        u64 wk = skey[i & 1][0];
#pragma unroll
        for (int j = 1; j < NWAVES; ++j) {
            const u64 ok = skey[i & 1][j];
            wk = (ok > wk) ? ok : wk;
        }
        const int wi = (int)(~(u32)wk);        // winner local index
        if (tid == 0) out[cloud * M + i] = base + wi;

        // ---- fetch winner coords (uniform address -> scalar load) ----
        const int wiu = __builtin_amdgcn_readfirstlane(wi);
        const float* qp = pos + (size_t)(base + wiu) * 3;
        const float qx = qp[0], qy = qp[1], qz = qp[2];
        qx2 = (v2f){qx, qx}; qy2 = (v2f){qy, qy}; qz2 = (v2f){qz, qz};

        // ---- fused distance update + lane-local argmax (ascending slots) ----
        bd = -1.0f; bk = 0;
#define UPD(j) { \
        v2f dx = px##j - qx2; \
        v2f dy = py##j - qy2; \
        v2f dz = pz##j - qz2; \
        v2f nd = dx * dx + dy * dy + dz * dz; \
        d##j.x = fminf(d##j.x, nd.x); \
        d##j.y = fminf(d##j.y, nd.y); \
        if (d##j.x > bd) { bd = d##j.x; bk = 2*(j); } \
        if (d##j.y > bd) { bd = d##j.y; bk = 2*(j) + 1; } \
    }
        GROUPS_X(UPD)
#undef UPD
    }
}

extern "C" void kernel_launch(void* const* d_in, const int* in_sizes, int n_in,
                              void* d_out, int out_size, void* d_ws, size_t ws_size,
                              hipStream_t stream) {
    const float* pos = (const float*)d_in[0];
    int* out = (int*)d_out;
    fps_kernel<<<N_CLOUDS, THREADS, 0, stream>>>(pos, out);
}

// Round 5
// 5831.327 us; speedup vs baseline: 1.1967x; 1.1967x over previous
//
#include <hip/hip_runtime.h>

#define N_CLOUDS 16
#define PTS      16384
#define M        4096
#define THREADS  512
#define NWAVES   (THREADS / 64)    // 8 waves
#define PPT      32                // consecutive points per thread

typedef float v2f __attribute__((ext_vector_type(2)));
typedef unsigned long long u64;
typedef unsigned int u32;

// One block per cloud; serial FPS, VALU-issue-optimized.
// Round-5 changes vs round 4 (which was 95% VALU-busy, 52 VGPRs => compiler
// was REMATERIALIZING point coords from L1/L2 every iteration):
//  - each thread owns 32 CONSECUTIVE points, loaded once as 24 float4 and
//    repacked into 48 v2f (x,y,z pairs); asm "+v" pin makes them opaque so
//    the compiler cannot remat-reload (and amdgpu_waves_per_eu(2,2) grants
//    the full 256-VGPR budget at 2 waves/SIMD).
//  - v2f arithmetic -> v_pk_add/mul_f32 (VOP3P), contract off => bit-exact.
//  - cross-wave reduce: lanes load skey[lane&7], 3 DPP max steps, readlane(7)
//    (~20 inst) instead of an all-threads 8-key u64 compare chain (~50).
// Kept: u64 key = (dist<<32)|~li (first-occurrence argmax), one barrier/iter
// with parity-buffered skey, DPP wave reduce, contract-off math (absmax=0).

#define PAIRS_X(X) X(0) X(1) X(2) X(3) X(4) X(5) X(6) X(7) \
                   X(8) X(9) X(10) X(11) X(12) X(13) X(14) X(15)
#define F24_X(X) X(0) X(1) X(2) X(3) X(4) X(5) X(6) X(7) X(8) X(9) X(10) X(11) \
                 X(12) X(13) X(14) X(15) X(16) X(17) X(18) X(19) X(20) X(21) X(22) X(23)
// QUAD(j0, j1, a, b, c): pairs j0=2m, j1=2m+1 from float4 f_a, f_b, f_c
// (points 4m..4m+3 = 12 consecutive floats x0 y0 z0 x1 y1 z1 x2 y2 z2 x3 y3 z3)
#define QUADS_X(X) X(0,1,0,1,2)     X(2,3,3,4,5)     X(4,5,6,7,8)     X(6,7,9,10,11) \
                   X(8,9,12,13,14)  X(10,11,15,16,17) X(12,13,18,19,20) X(14,15,21,22,23)

// u64 max-combine with DPP-shifted copy (old=0 is identity: keys >= 0)
#define DPP_MAX_STEP(key, CTRL) { \
        const u32 lo_  = (u32)(key); \
        const u32 hi_  = (u32)((key) >> 32); \
        const u32 lo2_ = (u32)__builtin_amdgcn_update_dpp(0, (int)lo_, (CTRL), 0xf, 0xf, false); \
        const u32 hi2_ = (u32)__builtin_amdgcn_update_dpp(0, (int)hi_, (CTRL), 0xf, 0xf, false); \
        const u64 ok_  = ((u64)hi2_ << 32) | lo2_; \
        (key) = (ok_ > (key)) ? ok_ : (key); \
    }

__global__ __launch_bounds__(THREADS)
__attribute__((amdgpu_waves_per_eu(2, 2)))
void fps_kernel(const float* __restrict__ pos, int* __restrict__ out)
{
#pragma clang fp contract(off)
    const int cloud = blockIdx.x;
    const int tid   = threadIdx.x;
    const int base  = cloud * PTS;

    __shared__ u64 skey[2][NWAVES];

    // ---- query = point 0 of cloud ----
    const float q0x = pos[(size_t)base * 3 + 0];
    const float q0y = pos[(size_t)base * 3 + 1];
    const float q0z = pos[(size_t)base * 3 + 2];
    v2f qx2 = {q0x, q0x}, qy2 = {q0y, q0y}, qz2 = {q0z, q0z};

    // ---- one-time vectorized load: 32 consecutive pts = 24 float4 ----
    const float4* pos4 = (const float4*)pos;
    const int fo = cloud * (PTS * 3 / 4) + tid * (PPT * 3 / 4);   // 24 float4/thread
#define LOADF(n) const float4 f##n = pos4[fo + (n)];
    F24_X(LOADF)
#undef LOADF

    // ---- repack into x/y/z pair registers (points 2j, 2j+1) ----
#define DECL(j) v2f XX##j, YY##j, ZZ##j, DD##j;
    PAIRS_X(DECL)
#undef DECL
#define REPACK(j0, j1, a, b, c) \
        XX##j0 = (v2f){f##a.x, f##a.w}; \
        YY##j0 = (v2f){f##a.y, f##b.x}; \
        ZZ##j0 = (v2f){f##a.z, f##b.y}; \
        XX##j1 = (v2f){f##b.z, f##c.y}; \
        YY##j1 = (v2f){f##b.w, f##c.z}; \
        ZZ##j1 = (v2f){f##c.x, f##c.w};
    QUADS_X(REPACK)
#undef REPACK

    // ---- pin coords in VGPRs: opaque defs => no remat, no reload ----
#define PIN8(a,b,c,d,e,g,h,k) asm volatile("" : "+v"(a),"+v"(b),"+v"(c),"+v"(d),"+v"(e),"+v"(g),"+v"(h),"+v"(k));
    PIN8(XX0, XX1, XX2, XX3, XX4, XX5, XX6, XX7)
    PIN8(XX8, XX9, XX10, XX11, XX12, XX13, XX14, XX15)
    PIN8(YY0, YY1, YY2, YY3, YY4, YY5, YY6, YY7)
    PIN8(YY8, YY9, YY10, YY11, YY12, YY13, YY14, YY15)
    PIN8(ZZ0, ZZ1, ZZ2, ZZ3, ZZ4, ZZ5, ZZ6, ZZ7)
    PIN8(ZZ8, ZZ9, ZZ10, ZZ11, ZZ12, ZZ13, ZZ14, ZZ15)
#undef PIN8

    // ---- init dists to point 0 + lane-local argmax ----
    float bd = -1.0f;   // running max of my min-dists
    int   bk = 0;       // slot 0..31; li = tid*PPT + bk
#define INITP(j) { \
        v2f dx = XX##j - qx2; \
        v2f dy = YY##j - qy2; \
        v2f dz = ZZ##j - qz2; \
        v2f nd = (dx * dx + dy * dy) + dz * dz; \
        DD##j = nd; \
        if (nd.x > bd) { bd = nd.x; bk = 2*(j); } \
        if (nd.y > bd) { bd = nd.y; bk = 2*(j) + 1; } \
    }
    PAIRS_X(INITP)
#undef INITP

    if (tid == 0) out[cloud * M] = base;   // first sample = point 0

    const int wave = tid >> 6;
    const int lane = tid & 63;

    for (int i = 1; i < M; ++i) {
        // ---- u64 key: high = dist bits (>=0, uint-monotone), low = ~li ----
        const int bi = tid * PPT + bk;
        u64 key = ((u64)__float_as_uint(bd) << 32) | (u32)(~bi);

        // ---- wave max-reduce via DPP; full max lands in lane 63 ----
        DPP_MAX_STEP(key, 0x111)   // row_shr:1
        DPP_MAX_STEP(key, 0x112)   // row_shr:2
        DPP_MAX_STEP(key, 0x114)   // row_shr:4
        DPP_MAX_STEP(key, 0x118)   // row_shr:8
        DPP_MAX_STEP(key, 0x142)   // row_bcast:15
        DPP_MAX_STEP(key, 0x143)   // row_bcast:31 -> lane 63 = wave max

        if (lane == 63) skey[i & 1][wave] = key;
        __syncthreads();

        // ---- cross-wave: lanes hold the 8 wave keys, 3 DPP steps, lane 7 ----
        u64 key2 = skey[i & 1][lane & 7];
        DPP_MAX_STEP(key2, 0x111)
        DPP_MAX_STEP(key2, 0x112)
        DPP_MAX_STEP(key2, 0x114)   // lane 7 = max of keys 0..7
        const u32 wlo = __builtin_amdgcn_readlane((u32)key2, 7);  // uniform
        const int wi  = (int)(~wlo);            // winner local index in cloud

        if (tid == 0) out[cloud * M + i] = base + wi;

        // ---- fetch winner coords (uniform address -> scalar loads) ----
        const float* qp = pos + (size_t)(base + wi) * 3;
        const float qx = qp[0], qy = qp[1], qz = qp[2];
        qx2 = (v2f){qx, qx}; qy2 = (v2f){qy, qy}; qz2 = (v2f){qz, qz};

        // ---- fused distance update + lane-local argmax (ascending slots) ----
        bd = -1.0f; bk = 0;
#define UPD(j) { \
        v2f dx = XX##j - qx2; \
        v2f dy = YY##j - qy2; \
        v2f dz = ZZ##j - qz2; \
        v2f nd = (dx * dx + dy * dy) + dz * dz; \
        DD##j.x = fminf(DD##j.x, nd.x); \
        DD##j.y = fminf(DD##j.y, nd.y); \
        if (DD##j.x > bd) { bd = DD##j.x; bk = 2*(j); } \
        if (DD##j.y > bd) { bd = DD##j.y; bk = 2*(j) + 1; } \
    }
        PAIRS_X(UPD)
#undef UPD
    }
}

extern "C" void kernel_launch(void* const* d_in, const int* in_sizes, int n_in,
                              void* d_out, int out_size, void* d_ws, size_t ws_size,
                              hipStream_t stream) {
    const float* pos = (const float*)d_in[0];
    int* out = (int*)d_out;
    fps_kernel<<<N_CLOUDS, THREADS, 0, stream>>>(pos, out);
}